// Round 1
// baseline (7425.412 us; speedup 1.0000x reference)
//
#include <hip/hip_runtime.h>
#include <math.h>

namespace {

constexpr int NUM_ENVS = 16384;
constexpr int NA = 16;       // agents per env
constexpr int ID = 128;      // input dim
constexpr int GH = 64;       // gcn hidden
constexpr int RH = 64;       // rnn hidden
constexpr int EPG = 128;     // edges per graph
constexpr int OUT_DIM = 512; // 16*4*8
constexpr int FLAT = NA * RH; // 1024

__device__ __forceinline__ float sigmoidf_(float v) {
    return 1.0f / (1.0f + expf(-v));
}

// Edge dtype detection: if edges are int64 (little-endian, values 0..15),
// every odd int32 word is a zero high-word. If int32, the odd words are
// uniform-random 0..15 edge indices; P(all 127 are zero) = 16^-127 ~ 0.
__global__ void detect_i64_kernel(const int* __restrict__ edges_i32,
                                  int* __restrict__ flag) {
    __shared__ int any_nonzero;
    if (threadIdx.x == 0) any_nonzero = 0;
    __syncthreads();
    if (edges_i32[2 * threadIdx.x + 1] != 0) atomicOr(&any_nonzero, 1);
    __syncthreads();
    if (threadIdx.x == 0) *flag = (any_nonzero == 0) ? 1 : 0;
}

// One block (256 threads) per env: GCNConv + single-step GRU, writes next_h.
__global__ __launch_bounds__(256) void fused_gcn_gru_kernel(
    const float* __restrict__ x,      // [E, 16, 128]
    const void*  __restrict__ edges,  // [E, 2, 128] int64 or int32
    const float* __restrict__ h_prev, // [E, 16, 64]
    const float* __restrict__ Wg,     // [128, 64]
    const float* __restrict__ bg,     // [64]
    const float* __restrict__ Wih,    // [192, 64]
    const float* __restrict__ Whh,    // [192, 64]
    const float* __restrict__ bih,    // [192]
    const float* __restrict__ bhh,    // [192]
    float* __restrict__ next_h,       // [E, 16, 64]
    const int* __restrict__ flag64)
{
    const int env = blockIdx.x;
    const int tid = threadIdx.x;

    __shared__ __align__(16) float x_s[NA * ID];    // 8 KiB
    __shared__ __align__(16) float xw_s[NA * GH];   // 4 KiB (xw, then gcn_out)
    __shared__ __align__(16) float h_s[NA * RH];    // 4 KiB
    __shared__ float agg_s[NA * 66];                // padded stride 66
    __shared__ int row_s[EPG];
    __shared__ int col_s[EPG];
    __shared__ float dinv_s[NA];
    __shared__ float invdeg_s[NA];
    __shared__ int deg_s[NA];

    // ---- stage x (2048 floats = 512 float4) and h (256 float4) ----
    {
        const float4* xg = (const float4*)(x + (size_t)env * (NA * ID));
        ((float4*)x_s)[tid] = xg[tid];
        ((float4*)x_s)[tid + 256] = xg[tid + 256];
        const float4* hg = (const float4*)(h_prev + (size_t)env * (NA * RH));
        ((float4*)h_s)[tid] = hg[tid];
    }
    // ---- stage edges (row = ei[env][0][:], col = ei[env][1][:]) ----
    const bool is64 = (*flag64 != 0);
    {
        long long v;
        if (tid < 128) {
            if (is64) v = ((const long long*)edges)[(size_t)env * 256 + tid];
            else      v = ((const int*)edges)[(size_t)env * 256 + tid];
            row_s[tid] = (int)v;
        } else {
            int t = tid - 128;
            if (is64) v = ((const long long*)edges)[(size_t)env * 256 + 128 + t];
            else      v = ((const int*)edges)[(size_t)env * 256 + 128 + t];
            col_s[t] = (int)v;
        }
    }
    if (tid < NA) deg_s[tid] = 0;
    __syncthreads();

    // ---- degree counts (self-loop +1 added later) ----
    if (tid < 128) atomicAdd(&deg_s[col_s[tid]], 1);

    // ---- xw = x @ W_gcn : lane j = out feature, ag = agent group ----
    const int j = tid & 63;
    const int ag = tid >> 6; // 0..3 (also the wave id)
    {
        float acc0 = 0.f, acc1 = 0.f, acc2 = 0.f, acc3 = 0.f;
        const float* x0 = &x_s[(ag * 4 + 0) * ID];
        const float* x1 = &x_s[(ag * 4 + 1) * ID];
        const float* x2 = &x_s[(ag * 4 + 2) * ID];
        const float* x3 = &x_s[(ag * 4 + 3) * ID];
        #pragma unroll 8
        for (int k = 0; k < ID; ++k) {
            const float w = Wg[k * GH + j]; // coalesced across lanes
            acc0 += x0[k] * w;
            acc1 += x1[k] * w;
            acc2 += x2[k] * w;
            acc3 += x3[k] * w;
        }
        xw_s[(ag * 4 + 0) * GH + j] = acc0;
        xw_s[(ag * 4 + 1) * GH + j] = acc1;
        xw_s[(ag * 4 + 2) * GH + j] = acc2;
        xw_s[(ag * 4 + 3) * GH + j] = acc3;
    }
    __syncthreads();

    if (tid < NA) {
        const float d = 1.0f + (float)deg_s[tid];
        dinv_s[tid] = rsqrtf(d);
        invdeg_s[tid] = 1.0f / d;
    }
    __syncthreads();

    // ---- init agg with self-loop term xw/deg ----
    #pragma unroll
    for (int i = 0; i < 4; ++i) {
        const int a = ag * 4 + i;
        agg_s[a * 66 + j] = xw_s[a * GH + j] * invdeg_s[a];
    }
    __syncthreads();

    // ---- edge scatter: each wave owns one edge per iteration ----
    #pragma unroll 4
    for (int it = 0; it < 32; ++it) {
        const int e = ag + 4 * it;
        const int r = row_s[e];
        const int c = col_s[e];
        const float nrm = dinv_s[r] * dinv_s[c];
        atomicAdd(&agg_s[c * 66 + j], nrm * xw_s[r * GH + j]);
    }
    __syncthreads();

    // ---- gcn_out = agg + b_gcn, stored back into xw_s ----
    {
        const float bgy = bg[j];
        #pragma unroll
        for (int i = 0; i < 4; ++i) {
            const int a = ag * 4 + i;
            xw_s[a * GH + j] = agg_s[a * 66 + j] + bgy;
        }
    }
    __syncthreads();

    // ---- GRU: lane owns hidden index j for agents ag*4..ag*4+3 ----
    float a_ir[4] = {0, 0, 0, 0}, a_iz[4] = {0, 0, 0, 0}, a_in[4] = {0, 0, 0, 0};
    float a_hr[4] = {0, 0, 0, 0}, a_hz[4] = {0, 0, 0, 0}, a_hn[4] = {0, 0, 0, 0};
    {
        const float* wir = Wih + (size_t)(0 + j) * RH;
        const float* wiz = Wih + (size_t)(64 + j) * RH;
        const float* win = Wih + (size_t)(128 + j) * RH;
        const float* whr = Whh + (size_t)(0 + j) * RH;
        const float* whz = Whh + (size_t)(64 + j) * RH;
        const float* whn = Whh + (size_t)(128 + j) * RH;
        #pragma unroll
        for (int k = 0; k < RH; k += 4) {
            const float4 vir = *(const float4*)(wir + k);
            const float4 viz = *(const float4*)(wiz + k);
            const float4 vin = *(const float4*)(win + k);
            const float4 vhr = *(const float4*)(whr + k);
            const float4 vhz = *(const float4*)(whz + k);
            const float4 vhn = *(const float4*)(whn + k);
            #pragma unroll
            for (int i = 0; i < 4; ++i) {
                const int a = ag * 4 + i;
                const float4 g = *(const float4*)&xw_s[a * GH + k];
                const float4 hh = *(const float4*)&h_s[a * RH + k];
                a_ir[i] += g.x * vir.x + g.y * vir.y + g.z * vir.z + g.w * vir.w;
                a_iz[i] += g.x * viz.x + g.y * viz.y + g.z * viz.z + g.w * viz.w;
                a_in[i] += g.x * vin.x + g.y * vin.y + g.z * vin.z + g.w * vin.w;
                a_hr[i] += hh.x * vhr.x + hh.y * vhr.y + hh.z * vhr.z + hh.w * vhr.w;
                a_hz[i] += hh.x * vhz.x + hh.y * vhz.y + hh.z * vhz.z + hh.w * vhz.w;
                a_hn[i] += hh.x * vhn.x + hh.y * vhn.y + hh.z * vhn.z + hh.w * vhn.w;
            }
        }
    }
    {
        const float bir = bih[j], biz = bih[64 + j], binn = bih[128 + j];
        const float bhr = bhh[j], bhz = bhh[64 + j], bhnn = bhh[128 + j];
        float* outp = next_h + (size_t)env * FLAT;
        #pragma unroll
        for (int i = 0; i < 4; ++i) {
            const int a = ag * 4 + i;
            const float r = sigmoidf_(a_ir[i] + bir + a_hr[i] + bhr);
            const float z = sigmoidf_(a_iz[i] + biz + a_hz[i] + bhz);
            const float n = tanhf(a_in[i] + binn + r * (a_hn[i] + bhnn));
            const float hp = h_s[a * RH + j];
            outp[a * RH + j] = (1.0f - z) * n + z * hp;
        }
    }
}

// logits[16384,512] = flat[16384,1024] @ W_lin^T + b_lin
// 64x64 output tile per block, K-tile 64, k-major LDS (stride 68 => aligned
// float4 reads, <=2-way bank conflicts).
__global__ __launch_bounds__(256) void logits_gemm_kernel(
    const float* __restrict__ A,    // [M, 1024] (= next_h flat)
    const float* __restrict__ W,    // [512, 1024]
    const float* __restrict__ bias, // [512]
    float* __restrict__ C)          // [M, 512]
{
    constexpr int LDT = 68;
    __shared__ __align__(16) float As[64 * LDT];
    __shared__ __align__(16) float Bs[64 * LDT];
    const int tid = threadIdx.x;
    const int m0 = blockIdx.y * 64;
    const int n0 = blockIdx.x * 64;
    const int tx = tid & 15;  // n micro-tile
    const int ty = tid >> 4;  // m micro-tile
    const int lm = tid >> 4;        // loader row 0..15
    const int lk4 = (tid & 15) * 4; // loader k offset

    float acc[4][4] = {};

    for (int k0 = 0; k0 < FLAT; k0 += 64) {
        __syncthreads();
        #pragma unroll
        for (int mm = 0; mm < 4; ++mm) {
            const int m = lm + 16 * mm;
            const float4 a4 = *(const float4*)&A[(size_t)(m0 + m) * FLAT + k0 + lk4];
            As[(lk4 + 0) * LDT + m] = a4.x;
            As[(lk4 + 1) * LDT + m] = a4.y;
            As[(lk4 + 2) * LDT + m] = a4.z;
            As[(lk4 + 3) * LDT + m] = a4.w;
            const float4 b4 = *(const float4*)&W[(size_t)(n0 + m) * FLAT + k0 + lk4];
            Bs[(lk4 + 0) * LDT + m] = b4.x;
            Bs[(lk4 + 1) * LDT + m] = b4.y;
            Bs[(lk4 + 2) * LDT + m] = b4.z;
            Bs[(lk4 + 3) * LDT + m] = b4.w;
        }
        __syncthreads();
        #pragma unroll 16
        for (int kk = 0; kk < 64; ++kk) {
            const float4 av = *(const float4*)&As[kk * LDT + ty * 4];
            const float4 bv = *(const float4*)&Bs[kk * LDT + tx * 4];
            acc[0][0] += av.x * bv.x; acc[0][1] += av.x * bv.y;
            acc[0][2] += av.x * bv.z; acc[0][3] += av.x * bv.w;
            acc[1][0] += av.y * bv.x; acc[1][1] += av.y * bv.y;
            acc[1][2] += av.y * bv.z; acc[1][3] += av.y * bv.w;
            acc[2][0] += av.z * bv.x; acc[2][1] += av.z * bv.y;
            acc[2][2] += av.z * bv.z; acc[2][3] += av.z * bv.w;
            acc[3][0] += av.w * bv.x; acc[3][1] += av.w * bv.y;
            acc[3][2] += av.w * bv.z; acc[3][3] += av.w * bv.w;
        }
    }

    const float4 b4 = *(const float4*)&bias[n0 + tx * 4];
    #pragma unroll
    for (int i = 0; i < 4; ++i) {
        float4 o;
        o.x = acc[i][0] + b4.x;
        o.y = acc[i][1] + b4.y;
        o.z = acc[i][2] + b4.z;
        o.w = acc[i][3] + b4.w;
        *(float4*)&C[(size_t)(m0 + ty * 4 + i) * OUT_DIM + n0 + tx * 4] = o;
    }
}

} // namespace

extern "C" void kernel_launch(void* const* d_in, const int* in_sizes, int n_in,
                              void* d_out, int out_size, void* d_ws, size_t ws_size,
                              hipStream_t stream) {
    const float* x    = (const float*)d_in[0];
    const void*  ei   = d_in[1];
    const float* h0   = (const float*)d_in[2];
    const float* Wg   = (const float*)d_in[3];
    const float* bg   = (const float*)d_in[4];
    const float* Wih  = (const float*)d_in[5];
    const float* Whh  = (const float*)d_in[6];
    const float* bih  = (const float*)d_in[7];
    const float* bhh  = (const float*)d_in[8];
    const float* Wlin = (const float*)d_in[9];
    const float* blin = (const float*)d_in[10];

    float* out = (float*)d_out;
    float* logits = out;                                   // [16384, 512]
    float* next_h = out + (size_t)NUM_ENVS * OUT_DIM;      // [16384, 16, 64]
    int* flag = (int*)d_ws;

    detect_i64_kernel<<<1, 128, 0, stream>>>((const int*)ei, flag);
    fused_gcn_gru_kernel<<<NUM_ENVS, 256, 0, stream>>>(
        x, ei, h0, Wg, bg, Wih, Whh, bih, bhh, next_h, flag);
    dim3 g2(OUT_DIM / 64, NUM_ENVS / 64);
    logits_gemm_kernel<<<g2, 256, 0, stream>>>(next_h, Wlin, blin, logits);
}

// Round 2
// 1332.708 us; speedup vs baseline: 5.5717x; 5.5717x over previous
//
#include <hip/hip_runtime.h>
#include <math.h>

namespace {

constexpr int NUM_ENVS = 16384;
constexpr int NA = 16;       // agents per env
constexpr int ID = 128;      // input dim
constexpr int GH = 64;       // gcn hidden
constexpr int RH = 64;       // rnn hidden
constexpr int EPG = 128;     // edges per graph
constexpr int OUT_DIM = 512; // 16*4*8
constexpr int FLAT = NA * RH; // 1024

__device__ __forceinline__ float sigmoidf_(float v) {
    return 1.0f / (1.0f + expf(-v));
}

// Block 0: edge dtype detection (int64 little-endian values 0..15 => every
// odd int32 word is zero; int32 random 0..15 => P(all zero) = 16^-127 ~ 0).
// Blocks 1..48: transpose W_ih/W_hh [192,64] -> k-major Wt [64,192] so GRU
// weight reads are lane-coalesced instead of 64-line row-gathers.
__global__ void prep_kernel(const int* __restrict__ edges_i32,
                            int* __restrict__ flag,
                            const float* __restrict__ Wih,
                            const float* __restrict__ Whh,
                            float* __restrict__ Wt_ih,
                            float* __restrict__ Wt_hh) {
    if (blockIdx.x == 0) {
        __shared__ int any_nonzero;
        if (threadIdx.x == 0) any_nonzero = 0;
        __syncthreads();
        if (threadIdx.x < 128 && edges_i32[2 * threadIdx.x + 1] != 0)
            atomicOr(&any_nonzero, 1);
        __syncthreads();
        if (threadIdx.x == 0) *flag = (any_nonzero == 0) ? 1 : 0;
        return;
    }
    const int t = ((int)blockIdx.x - 1) * 256 + (int)threadIdx.x; // 0..12287
    if (t < 64 * 192) {
        const int k = t / 192;
        const int r = t - k * 192;
        Wt_ih[t] = Wih[r * 64 + k];
        Wt_hh[t] = Whh[r * 64 + k];
    }
}

// One block (256 threads = 4 waves) per env: GCNConv + single-step GRU.
// Wave ag owns agents ag*4..ag*4+3; lane j owns hidden feature j.
__global__ __launch_bounds__(256, 4) void fused_gcn_gru_kernel(
    const float* __restrict__ x,      // [E, 16, 128]
    const void*  __restrict__ edges,  // [E, 2, 128] int64 or int32
    const float* __restrict__ h_prev, // [E, 16, 64]
    const float* __restrict__ Wg,     // [128, 64] (k-major already)
    const float* __restrict__ bg,     // [64]
    const float* __restrict__ Wt_ih,  // [64, 192] k-major (transposed)
    const float* __restrict__ Wt_hh,  // [64, 192] k-major
    const float* __restrict__ bih,    // [192]
    const float* __restrict__ bhh,    // [192]
    float* __restrict__ next_h,       // [E, 16, 64]
    const int* __restrict__ flag64)
{
    const int env = blockIdx.x;
    const int tid = threadIdx.x;
    const int j = tid & 63;   // lane / hidden feature
    const int ag = tid >> 6;  // wave id 0..3

    __shared__ __align__(16) float x_s[NA * ID];    // 8 KiB
    __shared__ __align__(16) float xw_s[NA * GH];   // 4 KiB (xw, then gcn_out)
    __shared__ __align__(16) float h_s[NA * RH];    // 4 KiB
    __shared__ float agg_s[NA * 66];                // padded stride 66
    __shared__ int row_s[EPG];
    __shared__ int col_s[EPG];
    __shared__ float dinv_s[NA];
    __shared__ float invdeg_s[NA];
    __shared__ int deg_s[NA];

    // ---- stage x (512 float4) and h (256 float4), coalesced ----
    {
        const float4* xg = (const float4*)(x + (size_t)env * (NA * ID));
        ((float4*)x_s)[tid] = xg[tid];
        ((float4*)x_s)[tid + 256] = xg[tid + 256];
        const float4* hg = (const float4*)(h_prev + (size_t)env * (NA * RH));
        ((float4*)h_s)[tid] = hg[tid];
    }
    // ---- stage edges ----
    const bool is64 = (*flag64 != 0);
    {
        long long v;
        if (tid < 128) {
            if (is64) v = ((const long long*)edges)[(size_t)env * 256 + tid];
            else      v = ((const int*)edges)[(size_t)env * 256 + tid];
            row_s[tid] = (int)v;
        } else {
            const int t = tid - 128;
            if (is64) v = ((const long long*)edges)[(size_t)env * 256 + 128 + t];
            else      v = ((const int*)edges)[(size_t)env * 256 + 128 + t];
            col_s[t] = (int)v;
        }
    }
    if (tid < NA) deg_s[tid] = 0;
    __syncthreads();

    // ---- degree counts (self-loop +1 later); overlapped with xw compute ----
    if (tid < 128) atomicAdd(&deg_s[col_s[tid]], 1);

    // ---- xw = x @ W_gcn ----
    {
        float acc0 = 0.f, acc1 = 0.f, acc2 = 0.f, acc3 = 0.f;
        const float* x0 = &x_s[(ag * 4 + 0) * ID];
        const float* x1 = &x_s[(ag * 4 + 1) * ID];
        const float* x2 = &x_s[(ag * 4 + 2) * ID];
        const float* x3 = &x_s[(ag * 4 + 3) * ID];
        #pragma unroll 2
        for (int k = 0; k < ID; k += 4) {
            const float4 v0 = *(const float4*)(x0 + k);  // LDS broadcast b128
            const float4 v1 = *(const float4*)(x1 + k);
            const float4 v2 = *(const float4*)(x2 + k);
            const float4 v3 = *(const float4*)(x3 + k);
            #pragma unroll
            for (int kk = 0; kk < 4; ++kk) {
                const float w = Wg[(k + kk) * GH + j];  // coalesced
                acc0 += (&v0.x)[kk] * w;
                acc1 += (&v1.x)[kk] * w;
                acc2 += (&v2.x)[kk] * w;
                acc3 += (&v3.x)[kk] * w;
            }
        }
        xw_s[(ag * 4 + 0) * GH + j] = acc0;
        xw_s[(ag * 4 + 1) * GH + j] = acc1;
        xw_s[(ag * 4 + 2) * GH + j] = acc2;
        xw_s[(ag * 4 + 3) * GH + j] = acc3;
    }
    __syncthreads();

    if (tid < NA) {
        const float d = 1.0f + (float)deg_s[tid];
        dinv_s[tid] = rsqrtf(d);
        invdeg_s[tid] = 1.0f / d;
    }
    __syncthreads();

    // ---- init agg with self-loop term xw/deg ----
    #pragma unroll
    for (int i = 0; i < 4; ++i) {
        const int a = ag * 4 + i;
        agg_s[a * 66 + j] = xw_s[a * GH + j] * invdeg_s[a];
    }
    __syncthreads();

    // ---- edge scatter: each wave owns one edge per iteration ----
    #pragma unroll 2
    for (int it = 0; it < 32; ++it) {
        const int e = ag + 4 * it;
        const int r = row_s[e];
        const int c = col_s[e];
        const float nrm = dinv_s[r] * dinv_s[c];
        atomicAdd(&agg_s[c * 66 + j], nrm * xw_s[r * GH + j]);
    }
    __syncthreads();

    // ---- gcn_out = agg + b_gcn, back into xw_s ----
    {
        const float bgy = bg[j];
        #pragma unroll
        for (int i = 0; i < 4; ++i) {
            const int a = ag * 4 + i;
            xw_s[a * GH + j] = agg_s[a * 66 + j] + bgy;
        }
    }
    __syncthreads();

    // ---- GRU with combined accumulators (16 total, no spill) ----
    float acc_r[4] = {0, 0, 0, 0};   // ir + hr
    float acc_z[4] = {0, 0, 0, 0};   // iz + hz
    float acc_n[4] = {0, 0, 0, 0};   // in
    float acc_hn[4] = {0, 0, 0, 0};  // hn (kept separate for r * (...))
    #pragma unroll 2
    for (int k = 0; k < RH; k += 4) {
        float4 g4[4], h4[4];
        #pragma unroll
        for (int i = 0; i < 4; ++i) {
            const int a = ag * 4 + i;
            g4[i] = *(const float4*)&xw_s[a * GH + k];  // LDS broadcast b128
            h4[i] = *(const float4*)&h_s[a * RH + k];
        }
        #pragma unroll
        for (int kk = 0; kk < 4; ++kk) {
            const float* wi = Wt_ih + (size_t)(k + kk) * 192;
            const float* wh = Wt_hh + (size_t)(k + kk) * 192;
            const float wir = wi[j], wiz = wi[64 + j], win = wi[128 + j];
            const float whr = wh[j], whz = wh[64 + j], whn = wh[128 + j];
            #pragma unroll
            for (int i = 0; i < 4; ++i) {
                const float g = (&g4[i].x)[kk];
                const float hh = (&h4[i].x)[kk];
                acc_r[i] += g * wir + hh * whr;
                acc_z[i] += g * wiz + hh * whz;
                acc_n[i] += g * win;
                acc_hn[i] += hh * whn;
            }
        }
    }
    {
        const float bir = bih[j], biz = bih[64 + j], binn = bih[128 + j];
        const float bhr = bhh[j], bhz = bhh[64 + j], bhnn = bhh[128 + j];
        float* outp = next_h + (size_t)env * FLAT;
        #pragma unroll
        for (int i = 0; i < 4; ++i) {
            const int a = ag * 4 + i;
            const float r = sigmoidf_(acc_r[i] + bir + bhr);
            const float z = sigmoidf_(acc_z[i] + biz + bhz);
            const float n = tanhf(acc_n[i] + binn + r * (acc_hn[i] + bhnn));
            const float hp = h_s[a * RH + j];
            outp[a * RH + j] = (1.0f - z) * n + z * hp;
        }
    }
}

// logits[16384,512] = flat[16384,1024] @ W_lin^T + b_lin
__global__ __launch_bounds__(256) void logits_gemm_kernel(
    const float* __restrict__ A,    // [M, 1024]
    const float* __restrict__ W,    // [512, 1024]
    const float* __restrict__ bias, // [512]
    float* __restrict__ C)          // [M, 512]
{
    constexpr int LDT = 68;
    __shared__ __align__(16) float As[64 * LDT];
    __shared__ __align__(16) float Bs[64 * LDT];
    const int tid = threadIdx.x;
    const int m0 = blockIdx.y * 64;
    const int n0 = blockIdx.x * 64;
    const int tx = tid & 15;  // n micro-tile
    const int ty = tid >> 4;  // m micro-tile
    const int lm = tid >> 4;        // loader row 0..15
    const int lk4 = (tid & 15) * 4; // loader k offset

    float acc[4][4] = {};

    for (int k0 = 0; k0 < FLAT; k0 += 64) {
        __syncthreads();
        #pragma unroll
        for (int mm = 0; mm < 4; ++mm) {
            const int m = lm + 16 * mm;
            const float4 a4 = *(const float4*)&A[(size_t)(m0 + m) * FLAT + k0 + lk4];
            As[(lk4 + 0) * LDT + m] = a4.x;
            As[(lk4 + 1) * LDT + m] = a4.y;
            As[(lk4 + 2) * LDT + m] = a4.z;
            As[(lk4 + 3) * LDT + m] = a4.w;
            const float4 b4 = *(const float4*)&W[(size_t)(n0 + m) * FLAT + k0 + lk4];
            Bs[(lk4 + 0) * LDT + m] = b4.x;
            Bs[(lk4 + 1) * LDT + m] = b4.y;
            Bs[(lk4 + 2) * LDT + m] = b4.z;
            Bs[(lk4 + 3) * LDT + m] = b4.w;
        }
        __syncthreads();
        #pragma unroll 16
        for (int kk = 0; kk < 64; ++kk) {
            const float4 av = *(const float4*)&As[kk * LDT + ty * 4];
            const float4 bv = *(const float4*)&Bs[kk * LDT + tx * 4];
            acc[0][0] += av.x * bv.x; acc[0][1] += av.x * bv.y;
            acc[0][2] += av.x * bv.z; acc[0][3] += av.x * bv.w;
            acc[1][0] += av.y * bv.x; acc[1][1] += av.y * bv.y;
            acc[1][2] += av.y * bv.z; acc[1][3] += av.y * bv.w;
            acc[2][0] += av.z * bv.x; acc[2][1] += av.z * bv.y;
            acc[2][2] += av.z * bv.z; acc[2][3] += av.z * bv.w;
            acc[3][0] += av.w * bv.x; acc[3][1] += av.w * bv.y;
            acc[3][2] += av.w * bv.z; acc[3][3] += av.w * bv.w;
        }
    }

    const float4 b4 = *(const float4*)&bias[n0 + tx * 4];
    #pragma unroll
    for (int i = 0; i < 4; ++i) {
        float4 o;
        o.x = acc[i][0] + b4.x;
        o.y = acc[i][1] + b4.y;
        o.z = acc[i][2] + b4.z;
        o.w = acc[i][3] + b4.w;
        *(float4*)&C[(size_t)(m0 + ty * 4 + i) * OUT_DIM + n0 + tx * 4] = o;
    }
}

} // namespace

extern "C" void kernel_launch(void* const* d_in, const int* in_sizes, int n_in,
                              void* d_out, int out_size, void* d_ws, size_t ws_size,
                              hipStream_t stream) {
    const float* x    = (const float*)d_in[0];
    const void*  ei   = d_in[1];
    const float* h0   = (const float*)d_in[2];
    const float* Wg   = (const float*)d_in[3];
    const float* bg   = (const float*)d_in[4];
    const float* Wih  = (const float*)d_in[5];
    const float* Whh  = (const float*)d_in[6];
    const float* bih  = (const float*)d_in[7];
    const float* bhh  = (const float*)d_in[8];
    const float* Wlin = (const float*)d_in[9];
    const float* blin = (const float*)d_in[10];

    float* out = (float*)d_out;
    float* logits = out;                                   // [16384, 512]
    float* next_h = out + (size_t)NUM_ENVS * OUT_DIM;      // [16384, 16, 64]

    float* wsf = (float*)d_ws;
    int* flag = (int*)wsf;                // 4 B
    float* Wt_ih = wsf + 64;              // [64,192] = 12288 floats
    float* Wt_hh = wsf + 64 + 12288;      // [64,192]

    prep_kernel<<<49, 256, 0, stream>>>((const int*)ei, flag,
                                        Wih, Whh, Wt_ih, Wt_hh);
    fused_gcn_gru_kernel<<<NUM_ENVS, 256, 0, stream>>>(
        x, ei, h0, Wg, bg, Wt_ih, Wt_hh, bih, bhh, next_h, flag);
    dim3 g2(OUT_DIM / 64, NUM_ENVS / 64);
    logits_gemm_kernel<<<g2, 256, 0, stream>>>(next_h, Wlin, blin, logits);
}

// Round 3
// 1127.667 us; speedup vs baseline: 6.5848x; 1.1818x over previous
//
#include <hip/hip_runtime.h>
#include <math.h>

namespace {

constexpr int NUM_ENVS = 16384;
constexpr int NA = 16;       // agents per env
constexpr int ID = 128;      // input dim
constexpr int GH = 64;       // gcn hidden
constexpr int RH = 64;       // rnn hidden
constexpr int EPG = 128;     // edges per graph
constexpr int OUT_DIM = 512; // 16*4*8
constexpr int FLAT = NA * RH; // 1024

typedef float floatx4 __attribute__((ext_vector_type(4)));
typedef short shortx8 __attribute__((ext_vector_type(8)));

__device__ __forceinline__ float sigmoidf_(float v) {
    return 1.0f / (1.0f + expf(-v));
}

__device__ __forceinline__ unsigned short f2bf(float f) {
    unsigned int u = __float_as_uint(f);
    u = (u + 0x7FFFu + ((u >> 16) & 1u)) >> 16;  // RNE
    return (unsigned short)u;
}

// ws float offsets
constexpr int WS_FLAG   = 0;
constexpr int WS_WGP    = 64;                    // [32][64][4]  = 8192 f
constexpr int WS_WPIH   = WS_WGP + 8192;         // [16][192][4] = 12288 f
constexpr int WS_WPHH   = WS_WPIH + 12288;       // [16][192][4] = 12288 f
constexpr int WS_WLB    = WS_WPHH + 12288;       // 524288 ushort = 262144 f
constexpr int WS_HB     = WS_WLB + 262144;       // 16777216 ushort = 8388608 f

// Block 0: edge dtype detect. Blocks 1..2176: weight repacks + bf16 convert.
//  - Wg_p[k4*256 + j*4 + kk]   = Wg[(4k4+kk)*64 + j]      (8192)
//  - Wp_ih[k4*768 + r*4 + kk]  = Wih[r*64 + 4k4+kk]       (12288)
//  - Wp_hh likewise                                        (12288)
//  - Wlb[u] = bf16(Wlin[u])                                (524288)
__global__ void prep_kernel(const int* __restrict__ edges_i32,
                            const float* __restrict__ Wg,
                            const float* __restrict__ Wih,
                            const float* __restrict__ Whh,
                            const float* __restrict__ Wlin,
                            float* __restrict__ ws) {
    if (blockIdx.x == 0) {
        __shared__ int any_nonzero;
        if (threadIdx.x == 0) any_nonzero = 0;
        __syncthreads();
        if (threadIdx.x < 128 && edges_i32[2 * threadIdx.x + 1] != 0)
            atomicOr(&any_nonzero, 1);
        __syncthreads();
        if (threadIdx.x == 0) ((int*)ws)[WS_FLAG] = (any_nonzero == 0) ? 1 : 0;
        return;
    }
    const int t = ((int)blockIdx.x - 1) * 256 + (int)threadIdx.x;
    if (t < 8192) {
        const int k4 = t >> 8, rem = t & 255, jj = rem >> 2, kk = rem & 3;
        ws[WS_WGP + t] = Wg[(k4 * 4 + kk) * 64 + jj];
    } else if (t < 20480) {
        const int u = t - 8192;
        const int k4 = u / 768, rem = u - k4 * 768, r = rem >> 2, kk = rem & 3;
        ws[WS_WPIH + u] = Wih[r * 64 + k4 * 4 + kk];
    } else if (t < 32768) {
        const int u = t - 20480;
        const int k4 = u / 768, rem = u - k4 * 768, r = rem >> 2, kk = rem & 3;
        ws[WS_WPHH + u] = Whh[r * 64 + k4 * 4 + kk];
    } else if (t < 32768 + 524288) {
        const int u = t - 32768;
        ((unsigned short*)(ws + WS_WLB))[u] = f2bf(Wlin[u]);
    }
}

// One block (256 threads = 4 waves) per env: GCNConv + single-step GRU.
__global__ __launch_bounds__(256, 4) void fused_gcn_gru_kernel(
    const float* __restrict__ x,      // [E, 16, 128]
    const void*  __restrict__ edges,  // [E, 2, 128] int64 or int32
    const float* __restrict__ h_prev, // [E, 16, 64]
    const float* __restrict__ Wg_p,   // packed [32][64][4]
    const float* __restrict__ bg,
    const float* __restrict__ Wp_ih,  // packed [16][192][4]
    const float* __restrict__ Wp_hh,  // packed [16][192][4]
    const float* __restrict__ bih,
    const float* __restrict__ bhh,
    float* __restrict__ next_h,       // [E, 16, 64] fp32 output
    unsigned short* __restrict__ hb,  // [E, 1024] bf16 copy for K2
    const int* __restrict__ flag64)
{
    const int env = blockIdx.x;
    const int tid = threadIdx.x;
    const int j = tid & 63;
    const int ag = tid >> 6;

    __shared__ __align__(16) float x_s[NA * ID];
    __shared__ __align__(16) float xw_s[NA * GH];
    __shared__ __align__(16) float h_s[NA * RH];
    __shared__ float agg_s[NA * 66];
    __shared__ int row_s[EPG];
    __shared__ int col_s[EPG];
    __shared__ float dinv_s[NA];
    __shared__ float invdeg_s[NA];
    __shared__ int deg_s[NA];

    {
        const float4* xg = (const float4*)(x + (size_t)env * (NA * ID));
        ((float4*)x_s)[tid] = xg[tid];
        ((float4*)x_s)[tid + 256] = xg[tid + 256];
        const float4* hg = (const float4*)(h_prev + (size_t)env * (NA * RH));
        ((float4*)h_s)[tid] = hg[tid];
    }
    const bool is64 = (*flag64 != 0);
    {
        long long v;
        if (tid < 128) {
            if (is64) v = ((const long long*)edges)[(size_t)env * 256 + tid];
            else      v = ((const int*)edges)[(size_t)env * 256 + tid];
            row_s[tid] = (int)v;
        } else {
            const int t = tid - 128;
            if (is64) v = ((const long long*)edges)[(size_t)env * 256 + 128 + t];
            else      v = ((const int*)edges)[(size_t)env * 256 + 128 + t];
            col_s[t] = (int)v;
        }
    }
    if (tid < NA) deg_s[tid] = 0;
    __syncthreads();

    if (tid < 128) atomicAdd(&deg_s[col_s[tid]], 1);

    // ---- xw = x @ W_gcn, packed float4 weight loads ----
    {
        float acc0 = 0.f, acc1 = 0.f, acc2 = 0.f, acc3 = 0.f;
        const float* x0 = &x_s[(ag * 4 + 0) * ID];
        const float* x1 = &x_s[(ag * 4 + 1) * ID];
        const float* x2 = &x_s[(ag * 4 + 2) * ID];
        const float* x3 = &x_s[(ag * 4 + 3) * ID];
        #pragma unroll 2
        for (int k4 = 0; k4 < 32; ++k4) {
            const float4 w = *(const float4*)&Wg_p[k4 * 256 + j * 4];
            const float4 v0 = *(const float4*)(x0 + k4 * 4);
            const float4 v1 = *(const float4*)(x1 + k4 * 4);
            const float4 v2 = *(const float4*)(x2 + k4 * 4);
            const float4 v3 = *(const float4*)(x3 + k4 * 4);
            acc0 += v0.x * w.x + v0.y * w.y + v0.z * w.z + v0.w * w.w;
            acc1 += v1.x * w.x + v1.y * w.y + v1.z * w.z + v1.w * w.w;
            acc2 += v2.x * w.x + v2.y * w.y + v2.z * w.z + v2.w * w.w;
            acc3 += v3.x * w.x + v3.y * w.y + v3.z * w.z + v3.w * w.w;
        }
        xw_s[(ag * 4 + 0) * GH + j] = acc0;
        xw_s[(ag * 4 + 1) * GH + j] = acc1;
        xw_s[(ag * 4 + 2) * GH + j] = acc2;
        xw_s[(ag * 4 + 3) * GH + j] = acc3;
    }
    __syncthreads();

    if (tid < NA) {
        const float d = 1.0f + (float)deg_s[tid];
        dinv_s[tid] = rsqrtf(d);
        invdeg_s[tid] = 1.0f / d;
    }
    __syncthreads();

    #pragma unroll
    for (int i = 0; i < 4; ++i) {
        const int a = ag * 4 + i;
        agg_s[a * 66 + j] = xw_s[a * GH + j] * invdeg_s[a];
    }
    __syncthreads();

    #pragma unroll 2
    for (int it = 0; it < 32; ++it) {
        const int e = ag + 4 * it;
        const int r = row_s[e];
        const int c = col_s[e];
        const float nrm = dinv_s[r] * dinv_s[c];
        atomicAdd(&agg_s[c * 66 + j], nrm * xw_s[r * GH + j]);
    }
    __syncthreads();

    {
        const float bgy = bg[j];
        #pragma unroll
        for (int i = 0; i < 4; ++i) {
            const int a = ag * 4 + i;
            xw_s[a * GH + j] = agg_s[a * 66 + j] + bgy;
        }
    }
    __syncthreads();

    // ---- GRU, packed float4 weight loads (6 per k4 instead of 24 scalars) ----
    float acc_r[4] = {0, 0, 0, 0};
    float acc_z[4] = {0, 0, 0, 0};
    float acc_n[4] = {0, 0, 0, 0};
    float acc_hn[4] = {0, 0, 0, 0};
    #pragma unroll 2
    for (int k4 = 0; k4 < 16; ++k4) {
        const float* wi = Wp_ih + k4 * 768;
        const float* wh = Wp_hh + k4 * 768;
        const float4 wir = *(const float4*)&wi[j * 4];
        const float4 wiz = *(const float4*)&wi[(64 + j) * 4];
        const float4 win = *(const float4*)&wi[(128 + j) * 4];
        const float4 whr = *(const float4*)&wh[j * 4];
        const float4 whz = *(const float4*)&wh[(64 + j) * 4];
        const float4 whn = *(const float4*)&wh[(128 + j) * 4];
        #pragma unroll
        for (int i = 0; i < 4; ++i) {
            const int a = ag * 4 + i;
            const float4 g = *(const float4*)&xw_s[a * GH + k4 * 4];
            const float4 hh = *(const float4*)&h_s[a * RH + k4 * 4];
            acc_r[i] += g.x * wir.x + g.y * wir.y + g.z * wir.z + g.w * wir.w
                      + hh.x * whr.x + hh.y * whr.y + hh.z * whr.z + hh.w * whr.w;
            acc_z[i] += g.x * wiz.x + g.y * wiz.y + g.z * wiz.z + g.w * wiz.w
                      + hh.x * whz.x + hh.y * whz.y + hh.z * whz.z + hh.w * whz.w;
            acc_n[i] += g.x * win.x + g.y * win.y + g.z * win.z + g.w * win.w;
            acc_hn[i] += hh.x * whn.x + hh.y * whn.y + hh.z * whn.z + hh.w * whn.w;
        }
    }
    {
        const float bir = bih[j], biz = bih[64 + j], binn = bih[128 + j];
        const float bhr = bhh[j], bhz = bhh[64 + j], bhnn = bhh[128 + j];
        float* outp = next_h + (size_t)env * FLAT;
        unsigned short* hbp = hb + (size_t)env * FLAT;
        #pragma unroll
        for (int i = 0; i < 4; ++i) {
            const int a = ag * 4 + i;
            const float r = sigmoidf_(acc_r[i] + bir + bhr);
            const float z = sigmoidf_(acc_z[i] + biz + bhz);
            const float n = tanhf(acc_n[i] + binn + r * (acc_hn[i] + bhnn));
            const float hp = h_s[a * RH + j];
            const float hv = (1.0f - z) * n + z * hp;
            outp[a * RH + j] = hv;
            hbp[a * RH + j] = f2bf(hv);
        }
    }
}

// logits[16384,512] = bf16(h_new)[16384,1024] @ Wlb[512,1024]^T + b_lin
// MFMA 16x16x32 bf16. 128x128 block tile, BK=64, XOR-swizzled LDS (no pad).
__global__ __launch_bounds__(256, 4) void logits_mfma_kernel(
    const unsigned short* __restrict__ A,  // [16384, 1024] bf16
    const unsigned short* __restrict__ B,  // [512, 1024] bf16 (row-major = [n][k])
    const float* __restrict__ bias,        // [512]
    float* __restrict__ C)                 // [16384, 512]
{
    __shared__ __align__(16) unsigned short As[128 * 64];  // 16 KiB
    __shared__ __align__(16) unsigned short Bs[128 * 64];  // 16 KiB

    const int tid = threadIdx.x;
    const int lane = tid & 63;
    const int wave = tid >> 6;
    const int wr = wave >> 1;  // 0..1
    const int wc = wave & 1;   // 0..1
    const int m0 = blockIdx.y * 128;
    const int n0 = blockIdx.x * 128;
    const int lr = tid >> 3;   // loader row 0..31
    const int lk = tid & 7;    // loader kgroup (16B units)

    floatx4 acc[4][4];
    #pragma unroll
    for (int i = 0; i < 4; ++i)
        #pragma unroll
        for (int jn = 0; jn < 4; ++jn)
            acc[i][jn] = (floatx4)(0.0f);

    for (int kt = 0; kt < 16; ++kt) {
        const int k0 = kt * 64;
        __syncthreads();
        #pragma unroll
        for (int i = 0; i < 4; ++i) {
            const int r = lr + 32 * i;
            const uint4 va = *(const uint4*)&A[(size_t)(m0 + r) * FLAT + k0 + lk * 8];
            *(uint4*)&As[r * 64 + ((lk ^ (r & 7)) * 8)] = va;
            const uint4 vb = *(const uint4*)&B[(size_t)(n0 + r) * FLAT + k0 + lk * 8];
            *(uint4*)&Bs[r * 64 + ((lk ^ (r & 7)) * 8)] = vb;
        }
        __syncthreads();
        #pragma unroll
        for (int s = 0; s < 2; ++s) {
            const int kg = s * 4 + (lane >> 4);
            const int sw = (kg ^ (lane & 7)) * 8;
            shortx8 af[4], bf[4];
            #pragma unroll
            for (int t = 0; t < 4; ++t) {
                af[t] = *(const shortx8*)&As[(wr * 64 + t * 16 + (lane & 15)) * 64 + sw];
                bf[t] = *(const shortx8*)&Bs[(wc * 64 + t * 16 + (lane & 15)) * 64 + sw];
            }
            #pragma unroll
            for (int mt = 0; mt < 4; ++mt)
                #pragma unroll
                for (int nt = 0; nt < 4; ++nt)
                    acc[mt][nt] = __builtin_amdgcn_mfma_f32_16x16x32_bf16(
                        af[mt], bf[nt], acc[mt][nt], 0, 0, 0);
        }
    }

    // epilogue: C/D layout col=lane&15, row=(lane>>4)*4+i
    const int col_l = lane & 15;
    const int rg = lane >> 4;
    #pragma unroll
    for (int nt = 0; nt < 4; ++nt) {
        const int col = n0 + wc * 64 + nt * 16 + col_l;
        const float bv = bias[col];
        #pragma unroll
        for (int mt = 0; mt < 4; ++mt) {
            const int row = m0 + wr * 64 + mt * 16 + rg * 4;
            #pragma unroll
            for (int i = 0; i < 4; ++i) {
                C[(size_t)(row + i) * OUT_DIM + col] = acc[mt][nt][i] + bv;
            }
        }
    }
}

} // namespace

extern "C" void kernel_launch(void* const* d_in, const int* in_sizes, int n_in,
                              void* d_out, int out_size, void* d_ws, size_t ws_size,
                              hipStream_t stream) {
    const float* x    = (const float*)d_in[0];
    const void*  ei   = d_in[1];
    const float* h0   = (const float*)d_in[2];
    const float* Wg   = (const float*)d_in[3];
    const float* bg   = (const float*)d_in[4];
    const float* Wih  = (const float*)d_in[5];
    const float* Whh  = (const float*)d_in[6];
    const float* bih  = (const float*)d_in[7];
    const float* bhh  = (const float*)d_in[8];
    const float* Wlin = (const float*)d_in[9];
    const float* blin = (const float*)d_in[10];

    float* out = (float*)d_out;
    float* logits = out;                                   // [16384, 512]
    float* next_h = out + (size_t)NUM_ENVS * OUT_DIM;      // [16384, 16, 64]

    float* wsf = (float*)d_ws;
    int* flag = (int*)(wsf + WS_FLAG);
    float* Wg_p  = wsf + WS_WGP;
    float* Wp_ih = wsf + WS_WPIH;
    float* Wp_hh = wsf + WS_WPHH;
    unsigned short* Wlb = (unsigned short*)(wsf + WS_WLB);
    unsigned short* hb  = (unsigned short*)(wsf + WS_HB);

    prep_kernel<<<2177, 256, 0, stream>>>((const int*)ei, Wg, Wih, Whh, Wlin, wsf);
    fused_gcn_gru_kernel<<<NUM_ENVS, 256, 0, stream>>>(
        x, ei, h0, Wg_p, bg, Wp_ih, Wp_hh, bih, bhh, next_h, hb, flag);
    dim3 g2(OUT_DIM / 128, NUM_ENVS / 128);
    logits_mfma_kernel<<<g2, 256, 0, stream>>>(hb, Wlb, blin, logits);
}

// Round 4
// 426.798 us; speedup vs baseline: 17.3980x; 2.6422x over previous
//
#include <hip/hip_runtime.h>
#include <math.h>

namespace {

constexpr int NUM_ENVS = 16384;
constexpr int OUT_DIM = 512;
constexpr int FLAT = 1024;

typedef float floatx4 __attribute__((ext_vector_type(4)));
typedef short shortx8 __attribute__((ext_vector_type(8)));

__device__ __forceinline__ float sigmoidf_(float v) {
    return 1.0f / (1.0f + expf(-v));
}
__device__ __forceinline__ unsigned short f2bf(float f) {
    unsigned int u = __float_as_uint(f);
    u = (u + 0x7FFFu + ((u >> 16) & 1u)) >> 16;  // RNE
    return (unsigned short)u;
}
__device__ __forceinline__ float bf2f(unsigned short s) {
    return __uint_as_float(((unsigned int)s) << 16);
}
__device__ __forceinline__ shortx8 pack8(const float4& f0, const float4& f1) {
    shortx8 o;
    o[0] = (short)f2bf(f0.x); o[1] = (short)f2bf(f0.y);
    o[2] = (short)f2bf(f0.z); o[3] = (short)f2bf(f0.w);
    o[4] = (short)f2bf(f1.x); o[5] = (short)f2bf(f1.y);
    o[6] = (short)f2bf(f1.z); o[7] = (short)f2bf(f1.w);
    return o;
}

// ws float offsets
constexpr int WS_FLAG = 0;
constexpr int WS_WGF  = 64;                  // 16 slots *64*8 = 8192 bf16 = 4096 f
constexpr int WS_WCF  = WS_WGF + 4096;       // 48 slots = 24576 bf16 = 12288 f
constexpr int WS_WLB  = WS_WCF + 12288;      // 524288 bf16 = 262144 f
constexpr int WS_GB   = WS_WLB + 262144;     // gcn/hb alias: 16777216 bf16

// prep: block 0 = edge dtype detect; rest pack MFMA B-fragments (bf16,
// per-lane order so kernels load frags with one coalesced 16B read).
__global__ void prep_kernel(const int* __restrict__ edges_i32,
                            const float* __restrict__ Wg,
                            const float* __restrict__ Wih,
                            const float* __restrict__ Whh,
                            const float* __restrict__ Wlin,
                            float* __restrict__ ws) {
    if (blockIdx.x == 0) {
        __shared__ int any_nonzero;
        if (threadIdx.x == 0) any_nonzero = 0;
        __syncthreads();
        if (threadIdx.x < 128 && edges_i32[2 * threadIdx.x + 1] != 0)
            atomicOr(&any_nonzero, 1);
        __syncthreads();
        if (threadIdx.x == 0) ((int*)ws)[WS_FLAG] = (any_nonzero == 0) ? 1 : 0;
        return;
    }
    const int t = ((int)blockIdx.x - 1) * 256 + (int)threadIdx.x;
    if (t < 8192) {
        // WgF: slot = nt*4+ks; B[n][k], n = Wg col, k = Wg row
        const int jj = t & 7, lane = (t >> 3) & 63, slot = t >> 9;
        const int nt = slot >> 2, ks = slot & 3;
        const int n = nt * 16 + (lane & 15);
        const int k = ks * 32 + ((lane >> 4) & 3) * 8 + jj;
        ((unsigned short*)(ws + WS_WGF))[t] = f2bf(Wg[k * 64 + n]);
    } else if (t < 32768) {
        const int u = t - 8192;
        const int jj = u & 7, lane = (u >> 3) & 63, slot = u >> 9; // 0..47
        const int q8 = ((lane >> 4) & 3) * 8 + jj;
        float val;
        if (slot < 16) {           // r gate, K=128 combined [Wih_r | Whh_r]
            const int nt = slot >> 2, ks = slot & 3;
            const int n = nt * 16 + (lane & 15);
            const int k = ks * 32 + q8;
            val = (k < 64) ? Wih[n * 64 + k] : Whh[n * 64 + (k - 64)];
        } else if (slot < 32) {    // z gate, K=128 combined
            const int s = slot - 16, nt = s >> 2, ks = s & 3;
            const int n = 64 + nt * 16 + (lane & 15);
            const int k = ks * 32 + q8;
            val = (k < 64) ? Wih[n * 64 + k] : Whh[n * 64 + (k - 64)];
        } else if (slot < 40) {    // nx: Wih_n, K=64
            const int s = slot - 32, nt = s >> 1, ks = s & 1;
            const int n = 128 + nt * 16 + (lane & 15);
            val = Wih[n * 64 + ks * 32 + q8];
        } else {                   // nh: Whh_n, K=64
            const int s = slot - 40, nt = s >> 1, ks = s & 1;
            const int n = 128 + nt * 16 + (lane & 15);
            val = Whh[n * 64 + ks * 32 + q8];
        }
        ((unsigned short*)(ws + WS_WCF))[u] = f2bf(val);
    } else if (t < 32768 + 524288) {
        const int u = t - 32768;
        ((unsigned short*)(ws + WS_WLB))[u] = f2bf(Wlin[u]);
    }
}

// K_A: 4 envs (64 node-rows) per block. xw = bf16(x)@Wg via MFMA, then
// GCN aggregation as dense adj[16x16]@xw per env. Writes gcn bf16.
__global__ __launch_bounds__(256, 3) void gcn_mfma_kernel(
    const float* __restrict__ x,
    const void*  __restrict__ edges,
    const unsigned short* __restrict__ WgF,
    const float* __restrict__ bg,
    unsigned short* __restrict__ gcn,   // [262144, 64] bf16
    const int* __restrict__ flag64)
{
    const int b = blockIdx.x;
    const int tid = threadIdx.x;
    const int lane = tid & 63;
    const int w = tid >> 6;

    __shared__ union {
        unsigned short xbf[64 * 136];   // staged x (bf16, pad 8)
        float xw[64 * 68];              // xw fp32 (same 17408 B)
    } U;
    __shared__ int row_s[512];
    __shared__ int col_s[512];
    __shared__ float adj_s[4][16][17];
    __shared__ int deg_s[4][16];
    __shared__ float dinv_s[4][16];
    __shared__ float invdeg_s[4][16];

    // zero adj/deg
    {
        float* ap = &adj_s[0][0][0];
        for (int i = tid; i < 4 * 16 * 17; i += 256) ap[i] = 0.0f;
        if (tid < 64) deg_s[tid >> 4][tid & 15] = 0;
    }
    // stage x -> bf16 LDS
    {
        const int r = tid >> 2, q = tid & 3;
        const float4* src = (const float4*)(x + ((size_t)b * 64 + r) * 128 + q * 32);
        unsigned short* dp = &U.xbf[r * 136 + q * 32];
        #pragma unroll
        for (int c = 0; c < 4; ++c) {
            const float4 f0 = src[2 * c], f1 = src[2 * c + 1];
            *(shortx8*)(dp + c * 8) = pack8(f0, f1);
        }
    }
    // stage edges (4 envs x 128)
    const bool is64 = (*flag64 != 0);
    #pragma unroll
    for (int t = 0; t < 2; ++t) {
        const int e = tid + 256 * t;
        const int el = e >> 7, idx = e & 127;
        const size_t base = ((size_t)b * 4 + el) * 256;
        int rv, cv;
        if (is64) {
            rv = (int)((const long long*)edges)[base + idx];
            cv = (int)((const long long*)edges)[base + 128 + idx];
        } else {
            rv = ((const int*)edges)[base + idx];
            cv = ((const int*)edges)[base + 128 + idx];
        }
        row_s[e] = rv; col_s[e] = cv;
    }
    __syncthreads();

    // degree atomics (overlap with MFMA below)
    #pragma unroll
    for (int t = 0; t < 2; ++t) {
        const int e = tid + 256 * t;
        atomicAdd(&deg_s[e >> 7][col_s[e]], 1);
    }

    // MFMA: wave w owns rows w*16..w*16+15, all 4 n-tiles
    shortx8 afr[4];
    #pragma unroll
    for (int ks = 0; ks < 4; ++ks)
        afr[ks] = *(const shortx8*)&U.xbf[(w * 16 + (lane & 15)) * 136 +
                                          ks * 32 + ((lane >> 4) & 3) * 8];
    floatx4 acc[4];
    #pragma unroll
    for (int nt = 0; nt < 4; ++nt) acc[nt] = (floatx4)(0.0f);
    #pragma unroll
    for (int nt = 0; nt < 4; ++nt) {
        #pragma unroll
        for (int ks = 0; ks < 4; ++ks) {
            const shortx8 bfr = *(const shortx8*)&WgF[((nt * 4 + ks) * 64 + lane) * 8];
            acc[nt] = __builtin_amdgcn_mfma_f32_16x16x32_bf16(afr[ks], bfr, acc[nt], 0, 0, 0);
        }
    }
    __syncthreads();  // all x reads + deg atomics complete

    if (tid < 64) {
        const float d = 1.0f + (float)deg_s[tid >> 4][tid & 15];
        dinv_s[tid >> 4][tid & 15] = rsqrtf(d);
        invdeg_s[tid >> 4][tid & 15] = 1.0f / d;
    }
    // store xw (aliases xbf; safe after barrier)
    #pragma unroll
    for (int nt = 0; nt < 4; ++nt)
        #pragma unroll
        for (int i = 0; i < 4; ++i)
            U.xw[(w * 16 + ((lane >> 4) & 3) * 4 + i) * 68 + nt * 16 + (lane & 15)] = acc[nt][i];
    __syncthreads();  // dinv + xw ready

    // adjacency accumulate
    #pragma unroll
    for (int t = 0; t < 2; ++t) {
        const int e = tid + 256 * t;
        const int el = e >> 7, r = row_s[e], c = col_s[e];
        atomicAdd(&adj_s[el][c][r], dinv_s[el][r] * dinv_s[el][c]);
    }
    if (tid < 64)
        atomicAdd(&adj_s[tid >> 4][tid & 15][tid & 15], invdeg_s[tid >> 4][tid & 15]);
    __syncthreads();

    // agg = adj @ xw, + bg, write bf16
    {
        const int ro = tid >> 2, q = tid & 3;
        const int el = ro >> 4, cl = ro & 15;
        float accs[16];
        #pragma unroll
        for (int m = 0; m < 16; ++m) accs[m] = 0.0f;
        for (int r16 = 0; r16 < 16; ++r16) {
            const float a = adj_s[el][cl][r16];
            const float4* xr = (const float4*)&U.xw[(el * 16 + r16) * 68 + q * 16];
            #pragma unroll
            for (int jq = 0; jq < 4; ++jq) {
                const float4 v = xr[jq];
                accs[4 * jq + 0] += a * v.x;
                accs[4 * jq + 1] += a * v.y;
                accs[4 * jq + 2] += a * v.z;
                accs[4 * jq + 3] += a * v.w;
            }
        }
        unsigned short* dst = gcn + ((size_t)b * 64 + ro) * 64 + q * 16;
        shortx8 o0, o1;
        #pragma unroll
        for (int m = 0; m < 8; ++m) o0[m] = (short)f2bf(accs[m] + bg[q * 16 + m]);
        #pragma unroll
        for (int m = 0; m < 8; ++m) o1[m] = (short)f2bf(accs[8 + m] + bg[q * 16 + 8 + m]);
        *(shortx8*)dst = o0;
        *(shortx8*)(dst + 8) = o1;
    }
}

// K_C: gates GEMM [gcn|h] @ Wcat^T (MFMA) + fused GRU epilogue.
// 64 rows/block; wave w owns rows w*16..w*16+15. r/z use K=128 combined;
// nx uses A cols 0-63 (gcn), nh uses cols 64-127 (h). C-layout puts
// r/z/nx/nh for a given (row, feat) in the same lane.
__global__ __launch_bounds__(256, 2) void gru_mfma_kernel(
    const unsigned short* __restrict__ gcn,  // [N,64] bf16
    const float* __restrict__ h_prev,        // [N,64] fp32
    const unsigned short* __restrict__ WcF,  // 48 frag slots
    const float* __restrict__ bih,
    const float* __restrict__ bhh,
    float* __restrict__ next_h,              // [N,64] fp32
    unsigned short* __restrict__ hb)         // [N,64] bf16 (aliases gcn)
{
    const int b = blockIdx.x;
    const int tid = threadIdx.x;
    const int lane = tid & 63;
    const int w = tid >> 6;

    __shared__ unsigned short A_s[64 * 136];      // 17408 B
    __shared__ unsigned short W_s[48 * 64 * 8];   // 49152 B

    // stage W fragments (48 KiB, coalesced)
    {
        const uint4* src = (const uint4*)WcF;
        uint4* dst = (uint4*)W_s;
        #pragma unroll
        for (int jq = 0; jq < 12; ++jq) dst[tid + 256 * jq] = src[tid + 256 * jq];
    }
    // stage A: cols 0-63 <- gcn bf16, cols 64-127 <- cvt(h fp32)
    {
        const int r = tid >> 2, q = tid & 3;
        if (q < 2) {
            const uint4* src = (const uint4*)(gcn + ((size_t)b * 64 + r) * 64 + q * 32);
            uint4* dst = (uint4*)&A_s[r * 136 + q * 32];
            #pragma unroll
            for (int jq = 0; jq < 4; ++jq) dst[jq] = src[jq];
        } else {
            const float4* src = (const float4*)(h_prev + ((size_t)b * 64 + r) * 64 + (q - 2) * 32);
            unsigned short* dp = &A_s[r * 136 + 64 + (q - 2) * 32];
            #pragma unroll
            for (int c = 0; c < 4; ++c) {
                const float4 f0 = src[2 * c], f1 = src[2 * c + 1];
                *(shortx8*)(dp + c * 8) = pack8(f0, f1);
            }
        }
    }
    __syncthreads();

    shortx8 afr[4];
    #pragma unroll
    for (int ks = 0; ks < 4; ++ks)
        afr[ks] = *(const shortx8*)&A_s[(w * 16 + (lane & 15)) * 136 +
                                        ks * 32 + ((lane >> 4) & 3) * 8];
    floatx4 aR[4], aZ[4], aNX[4], aNH[4];
    #pragma unroll
    for (int nt = 0; nt < 4; ++nt) {
        aR[nt] = (floatx4)(0.0f); aZ[nt] = (floatx4)(0.0f);
        aNX[nt] = (floatx4)(0.0f); aNH[nt] = (floatx4)(0.0f);
    }
    #pragma unroll
    for (int nt = 0; nt < 4; ++nt) {
        #pragma unroll
        for (int ks = 0; ks < 4; ++ks) {
            const shortx8 bfr = *(const shortx8*)&W_s[((nt * 4 + ks) * 64 + lane) * 8];
            aR[nt] = __builtin_amdgcn_mfma_f32_16x16x32_bf16(afr[ks], bfr, aR[nt], 0, 0, 0);
        }
        #pragma unroll
        for (int ks = 0; ks < 4; ++ks) {
            const shortx8 bfr = *(const shortx8*)&W_s[((16 + nt * 4 + ks) * 64 + lane) * 8];
            aZ[nt] = __builtin_amdgcn_mfma_f32_16x16x32_bf16(afr[ks], bfr, aZ[nt], 0, 0, 0);
        }
        #pragma unroll
        for (int ks = 0; ks < 2; ++ks) {
            const shortx8 bfr = *(const shortx8*)&W_s[((32 + nt * 2 + ks) * 64 + lane) * 8];
            aNX[nt] = __builtin_amdgcn_mfma_f32_16x16x32_bf16(afr[ks], bfr, aNX[nt], 0, 0, 0);
        }
        #pragma unroll
        for (int ks = 0; ks < 2; ++ks) {
            const shortx8 bfr = *(const shortx8*)&W_s[((40 + nt * 2 + ks) * 64 + lane) * 8];
            aNH[nt] = __builtin_amdgcn_mfma_f32_16x16x32_bf16(afr[ks + 2], bfr, aNH[nt], 0, 0, 0);
        }
    }

    // GRU epilogue (all in-lane)
    const int cl = lane & 15;
    const int rq = (lane >> 4) & 3;
    #pragma unroll
    for (int tp = 0; tp < 4; ++tp) {
        const int f = tp * 16 + cl;
        const float br = bih[f] + bhh[f];
        const float bz = bih[64 + f] + bhh[64 + f];
        const float bnx = bih[128 + f];
        const float bnh = bhh[128 + f];
        #pragma unroll
        for (int i = 0; i < 4; ++i) {
            const int rl = w * 16 + rq * 4 + i;
            const size_t row = (size_t)b * 64 + rl;
            const float hp = bf2f(A_s[rl * 136 + 64 + f]);
            const float r = sigmoidf_(aR[tp][i] + br);
            const float z = sigmoidf_(aZ[tp][i] + bz);
            const float n = tanhf(aNX[tp][i] + bnx + r * (aNH[tp][i] + bnh));
            const float hv = (1.0f - z) * n + z * hp;
            next_h[row * 64 + f] = hv;
            hb[row * 64 + f] = f2bf(hv);
        }
    }
}

// K_D: logits = hb[16384,1024] @ Wlb[512,1024]^T + b_lin (unchanged)
__global__ __launch_bounds__(256, 4) void logits_mfma_kernel(
    const unsigned short* __restrict__ A,
    const unsigned short* __restrict__ B,
    const float* __restrict__ bias,
    float* __restrict__ C)
{
    __shared__ __align__(16) unsigned short As[128 * 64];
    __shared__ __align__(16) unsigned short Bs[128 * 64];

    const int tid = threadIdx.x;
    const int lane = tid & 63;
    const int wave = tid >> 6;
    const int wr = wave >> 1;
    const int wc = wave & 1;
    const int m0 = blockIdx.y * 128;
    const int n0 = blockIdx.x * 128;
    const int lr = tid >> 3;
    const int lk = tid & 7;

    floatx4 acc[4][4];
    #pragma unroll
    for (int i = 0; i < 4; ++i)
        #pragma unroll
        for (int jn = 0; jn < 4; ++jn)
            acc[i][jn] = (floatx4)(0.0f);

    for (int kt = 0; kt < 16; ++kt) {
        const int k0 = kt * 64;
        __syncthreads();
        #pragma unroll
        for (int i = 0; i < 4; ++i) {
            const int r = lr + 32 * i;
            const uint4 va = *(const uint4*)&A[(size_t)(m0 + r) * FLAT + k0 + lk * 8];
            *(uint4*)&As[r * 64 + ((lk ^ (r & 7)) * 8)] = va;
            const uint4 vb = *(const uint4*)&B[(size_t)(n0 + r) * FLAT + k0 + lk * 8];
            *(uint4*)&Bs[r * 64 + ((lk ^ (r & 7)) * 8)] = vb;
        }
        __syncthreads();
        #pragma unroll
        for (int s = 0; s < 2; ++s) {
            const int kg = s * 4 + (lane >> 4);
            const int sw = (kg ^ (lane & 7)) * 8;
            shortx8 af[4], bf[4];
            #pragma unroll
            for (int t = 0; t < 4; ++t) {
                af[t] = *(const shortx8*)&As[(wr * 64 + t * 16 + (lane & 15)) * 64 + sw];
                bf[t] = *(const shortx8*)&Bs[(wc * 64 + t * 16 + (lane & 15)) * 64 + sw];
            }
            #pragma unroll
            for (int mt = 0; mt < 4; ++mt)
                #pragma unroll
                for (int nt = 0; nt < 4; ++nt)
                    acc[mt][nt] = __builtin_amdgcn_mfma_f32_16x16x32_bf16(
                        af[mt], bf[nt], acc[mt][nt], 0, 0, 0);
        }
    }

    const int col_l = lane & 15;
    const int rg = lane >> 4;
    #pragma unroll
    for (int nt = 0; nt < 4; ++nt) {
        const int col = n0 + wc * 64 + nt * 16 + col_l;
        const float bv = bias[col];
        #pragma unroll
        for (int mt = 0; mt < 4; ++mt) {
            const int row = m0 + wr * 64 + mt * 16 + rg * 4;
            #pragma unroll
            for (int i = 0; i < 4; ++i) {
                C[(size_t)(row + i) * OUT_DIM + col] = acc[mt][nt][i] + bv;
            }
        }
    }
}

} // namespace

extern "C" void kernel_launch(void* const* d_in, const int* in_sizes, int n_in,
                              void* d_out, int out_size, void* d_ws, size_t ws_size,
                              hipStream_t stream) {
    const float* x    = (const float*)d_in[0];
    const void*  ei   = d_in[1];
    const float* h0   = (const float*)d_in[2];
    const float* Wg   = (const float*)d_in[3];
    const float* bg   = (const float*)d_in[4];
    const float* Wih  = (const float*)d_in[5];
    const float* Whh  = (const float*)d_in[6];
    const float* bih  = (const float*)d_in[7];
    const float* bhh  = (const float*)d_in[8];
    const float* Wlin = (const float*)d_in[9];
    const float* blin = (const float*)d_in[10];

    float* out = (float*)d_out;
    float* logits = out;                               // [16384, 512]
    float* next_h = out + (size_t)NUM_ENVS * OUT_DIM;  // [16384, 16, 64]

    float* wsf = (float*)d_ws;
    int* flag = (int*)(wsf + WS_FLAG);
    unsigned short* WgF = (unsigned short*)(wsf + WS_WGF);
    unsigned short* WcF = (unsigned short*)(wsf + WS_WCF);
    unsigned short* Wlb = (unsigned short*)(wsf + WS_WLB);
    unsigned short* gb  = (unsigned short*)(wsf + WS_GB);  // gcn, then hb

    prep_kernel<<<2177, 256, 0, stream>>>((const int*)ei, Wg, Wih, Whh, Wlin, wsf);
    gcn_mfma_kernel<<<4096, 256, 0, stream>>>(x, ei, WgF, bg, gb, flag);
    gru_mfma_kernel<<<4096, 256, 0, stream>>>(gb, h0, WcF, bih, bhh, next_h, gb);
    dim3 g2(OUT_DIM / 128, NUM_ENVS / 128);
    logits_mfma_kernel<<<g2, 256, 0, stream>>>(gb, Wlb, blin, logits);
}